// Round 19
// baseline (620.819 us; speedup 1.0000x reference)
//
#include <hip/hip_runtime.h>
#include <hip/hip_fp16.h>

#define T_STEPS 2048
#define BATCH   128
#define HID     100     // LSTM hidden size
#define KP      128     // padded K: [0..99]=h (fp8), 100..127 = 0
#define NTH     448     // 7 waves; MFMA counts 4,4,4,4,3,3,3 -> exactly 100 units

#define LOG2E 1.44269504088896340736f

typedef int   i32x8 __attribute__((ext_vector_type(8)));
typedef float f32x4 __attribute__((ext_vector_type(4)));

// DPP quad_perm helpers (VALU pipe, immediate ctrl)
template <int CTRL>
__device__ __forceinline__ float dpp_mov(float v) {
    int y = __builtin_amdgcn_update_dpp(0, __float_as_int(v), CTRL, 0xF, 0xF, true);
    return __int_as_float(y);
}

__global__ __launch_bounds__(NTH)
void lstm_caviar_kernel(
    const float* __restrict__ x,      // [T, B, 1]
    const float* __restrict__ W_ih,   // [400, 1]
    const float* __restrict__ W_hh,   // [400, 100]
    const float* __restrict__ b_ih,   // [400]
    const float* __restrict__ b_hh,   // [400]
    const float* __restrict__ W1,     // [64, 100]
    const float* __restrict__ b1,     // [64]
    const float* __restrict__ W2,     // [1, 64]
    const float* __restrict__ b2,     // [1]
    float* __restrict__ out)          // [1]
{
    // h as fp8 e4m3 (double-buffered, 128 B each): one barrier per step.
    __shared__ __align__(32) unsigned char hbuf[2][KP];
    __shared__ float hfin[KP];        // f32 h (written once, after the loop)
    __shared__ __align__(8) float x_lds[T_STEPS];
    __shared__ float red_lds[64];

    const int tid  = threadIdx.x;
    const int w    = tid >> 6;        // wave id 0..6
    const int n    = tid & 15;        // MFMA col (C/D: col = lane&15, m89)
    const int gate = n & 3;           // this lane's gate (0=i,1=f,2=g~,3=o)
    const int usub = n >> 2;          // unit-sub within a 4-unit column group
    const int l16  = (tid >> 4) & 3;  // k-group for fragments AND col-group q

    // Unequal MFMA distribution (zero column padding): waves 0-3 issue 4
    // MFMAs (16 units each: 0..63), waves 4-6 issue 3 (12 units each:
    // 64..99). Busiest SIMD: 4+3 = 7 MFMAs/step — the provable floor
    // (25 MFMAs minimal for 400 outputs at 16 cols/MFMA; ceil(25/4)=7).
    const bool w4     = (w < 4);
    const int  base   = w4 ? (16 * w) : (64 + 12 * (w - 4));
    const bool qvalid = w4 || (l16 < 3);        // lane has a (gate,unit) pair?
    const int  unit   = base + 4 * l16 + usub;  // valid iff qvalid (<100 then)
    const bool writer = (gate == 0) && qvalid;
    const bool is_g   = (gate == 2);

    // stage batch-0 inputs (x[t,0,0] = flat[t*BATCH]) into LDS once
    for (int t = tid; t < T_STEPS; t += NTH)
        x_lds[t] = x[t * BATCH];
    if (tid < KP) { hbuf[0][tid] = 0; hbuf[1][tid] = 0; }

    // Static B fragments (fp8 e4m3), one per column-group q. Lane's 32 bytes
    // cover k = l16*32 + d*4 + byte — SAME k-labeling as A, so any mismatch vs
    // the true HW k-mapping cancels in the K-contraction (HW-validated R10+).
    // Rows pre-scaled by log2e (2x for gate g~) so activations use raw exp2.
    // Bias + W_ih*x enter as a negated scalar np merged in the activation:
    // exp2(-tot) = exp2(np - raw). MFMA C-in is a persistent zero vector.
    i32x8 bfr[4];
    #pragma unroll
    for (int q = 0; q < 4; ++q) {
        const int uu = base + 4 * q + usub;     // unit of this lane's col in MFMA q
        const bool uv = (uu < HID);
        const int r  = gate * HID + (uv ? uu : 0);
        const float Lg = is_g ? (2.0f * LOG2E) : LOG2E;
        i32x8 f;
        #pragma unroll
        for (int d = 0; d < 8; ++d) {
            const int k0 = l16 * 32 + d * 4;
            float v0 = 0.f, v1 = 0.f, v2 = 0.f, v3 = 0.f;
            if (uv) {
                if (k0     < HID) v0 = Lg * W_hh[r * HID + k0];
                if (k0 + 1 < HID) v1 = Lg * W_hh[r * HID + k0 + 1];
                if (k0 + 2 < HID) v2 = Lg * W_hh[r * HID + k0 + 2];
                if (k0 + 3 < HID) v3 = Lg * W_hh[r * HID + k0 + 3];
            }
            int reg = __builtin_amdgcn_cvt_pk_fp8_f32(v0, v1, 0,   false);
            reg     = __builtin_amdgcn_cvt_pk_fp8_f32(v2, v3, reg, true);
            f[d] = reg;
        }
        bfr[q] = f;
    }
    // own (gate, unit) bias/input coefficients (negated, pre-scaled)
    const int rown = gate * HID + (qvalid ? unit : 0);
    const float Lgo = is_g ? (2.0f * LOG2E) : LOG2E;
    const float nwi = qvalid ? -Lgo * W_ih[rown] : 0.0f;
    const float nbs = qvalid ? -Lgo * (b_ih[rown] + b_hh[rown]) : 0.0f;

    float c = 0.0f;
    float h = 0.0f;
    // hoisted per-lane addresses: substep entry is a pure ds_read
    const unsigned char* pA = hbuf[0] + l16 * 32;
    const unsigned char* pB = hbuf[1] + l16 * 32;
    unsigned char* wA = hbuf[0] + (qvalid ? unit : 0);
    unsigned char* wB = hbuf[1] + (qvalid ? unit : 0);
    const f32x4 czero = {0.f, 0.f, 0.f, 0.f};
    const bool lb0 = (l16 & 1) != 0;
    const bool lb1 = (l16 & 2) != 0;
    __syncthreads();

    // One LSTM step: read fp8 h via pr, write new fp8 h via pw.
    // np precomputed at iteration top (off the critical entry path).
    auto step = [&](const unsigned char* pr, unsigned char* pw, const float np) {
        // A = h broadcast to all 16 rows: one 32-B broadcast read per lane.
        const i32x8 av = *(const i32x8*)pr;

        // 3 or 4 MFMAs, K=128 each, C-in = zero (scales = 1.0: e8m0 0x7F)
        const f32x4 a0 = __builtin_amdgcn_mfma_scale_f32_16x16x128_f8f6f4(
                 av, bfr[0], czero, 0, 0, 0, 0x7F7F7F7F, 0, 0x7F7F7F7F);
        const f32x4 a1 = __builtin_amdgcn_mfma_scale_f32_16x16x128_f8f6f4(
                 av, bfr[1], czero, 0, 0, 0, 0x7F7F7F7F, 0, 0x7F7F7F7F);
        const f32x4 a2 = __builtin_amdgcn_mfma_scale_f32_16x16x128_f8f6f4(
                 av, bfr[2], czero, 0, 0, 0, 0x7F7F7F7F, 0, 0x7F7F7F7F);
        f32x4 a3 = czero;
        if (w4)                            // wave-uniform branch
            a3 = __builtin_amdgcn_mfma_scale_f32_16x16x128_f8f6f4(
                 av, bfr[3], czero, 0, 0, 0, 0x7F7F7F7F, 0, 0x7F7F7F7F);

        // this lane's raw = column-group q == l16 (rows identical -> reg 0)
        const float t0  = lb0 ? a1[0] : a0[0];
        const float t1  = lb0 ? a3[0] : a2[0];
        const float raw = lb1 ? t1 : t0;

        // ONE activation per lane (own gate): sigmoid, or tanh for g~
        const float e   = __builtin_amdgcn_exp2f(np - raw);
        const float r   = __builtin_amdgcn_rcpf(1.0f + e);
        const float act = is_g ? fmaf(2.0f, r, -1.0f) : r;

        // 2-DPP c-update: lane0's quad-swap product = i*g; writer is gate 0.
        const float prod = act * dpp_mov<0x4E>(act);
        const float fg   = dpp_mov<0x55>(act);
        c = fmaf(fg, c, prod);
        const float th = fmaf(2.0f, __builtin_amdgcn_rcpf(
                              1.0f + __builtin_amdgcn_exp2f(-2.0f * LOG2E * c)), -1.0f);
        const float og = dpp_mov<0xFF>(act);
        h = og * th;

        if (writer) {
            const int pk = __builtin_amdgcn_cvt_pk_fp8_f32(h, 0.0f, 0, false);
            *pw = (unsigned char)pk;       // ds_write_b8 takes low 8 bits
        }
        __syncthreads();
    };

    for (int t = 0; t < T_STEPS; t += 2) {
        // both substeps' x + bias terms computed up front, off the chain
        const float2 xp = *(const float2*)(x_lds + t);
        const float npA = fmaf(nwi, xp.x, nbs);
        const float npB = fmaf(nwi, xp.y, nbs);
        step(pA, wB, npA);
        step(pB, wA, npB);
    }

    // final h (f32, full precision) for the head — written once
    if (writer) hfin[unit] = h;
    if (tid >= HID && tid < KP) hfin[tid] = 0.0f;
    __syncthreads();

    // head: lin = W1 @ h + b1 (64), out = W2 @ lin + b2 (scalar) — f32 h
    if (tid < 64) {
        const float* rw = W1 + tid * HID;
        float a = 0.0f;
        for (int k = 0; k < HID; ++k)
            a = fmaf(rw[k], hfin[k], a);
        red_lds[tid] = a + b1[tid];
    }
    __syncthreads();
    if (tid == 0) {
        float a = b2[0];
        for (int k = 0; k < 64; ++k)
            a = fmaf(W2[k], red_lds[k], a);
        out[0] = a;
    }
}

extern "C" void kernel_launch(void* const* d_in, const int* in_sizes, int n_in,
                              void* d_out, int out_size, void* d_ws, size_t ws_size,
                              hipStream_t stream) {
    lstm_caviar_kernel<<<1, NTH, 0, stream>>>(
        (const float*)d_in[0],  // input_seq
        (const float*)d_in[1],  // W_ih
        (const float*)d_in[2],  // W_hh
        (const float*)d_in[3],  // b_ih
        (const float*)d_in[4],  // b_hh
        (const float*)d_in[5],  // W1
        (const float*)d_in[6],  // b1
        (const float*)d_in[7],  // W2
        (const float*)d_in[8],  // b2
        (float*)d_out);
}